// Round 7
// baseline (787.999 us; speedup 1.0000x reference)
//
#include <hip/hip_runtime.h>
#include <hip/hip_fp16.h>
#include <math.h>

#define NN 100000
#define EE 1600000
#define NEG 0.2f
#define NB 98     // ceil(NN/1024) scan blocks
#define STRIP 128 // nodes per gemm1 block
#define GB 782    // gemm blocks = ceil(NN/STRIP)
#define HB 6250   // hist blocks = ceil(EE/256)

typedef _Float16 fh8 __attribute__((ext_vector_type(8)));
typedef float f32x4 __attribute__((ext_vector_type(4)));

__device__ __forceinline__ float lrelu(float v) { return v > 0.f ? v : NEG * v; }

__device__ __forceinline__ void fma8(const uint4& r, float w, float* acc)
{
    float2 f0 = __half22float2(*(const __half2*)&r.x);
    float2 f1 = __half22float2(*(const __half2*)&r.y);
    float2 f2 = __half22float2(*(const __half2*)&r.z);
    float2 f3 = __half22float2(*(const __half2*)&r.w);
    acc[0] = fmaf(w, f0.x, acc[0]); acc[1] = fmaf(w, f0.y, acc[1]);
    acc[2] = fmaf(w, f1.x, acc[2]); acc[3] = fmaf(w, f1.y, acc[3]);
    acc[4] = fmaf(w, f2.x, acc[4]); acc[5] = fmaf(w, f2.y, acc[5]);
    acc[6] = fmaf(w, f3.x, acc[6]); acc[7] = fmaf(w, f3.y, acc[7]);
}

// ---------------- prep: pack W1 into MFMA A-frag order + BN affine combine ----------------
__global__ void prep_kernel(const float* __restrict__ W1,
                            const float* __restrict__ b1, const float* __restrict__ gamma,
                            const float* __restrict__ beta, const float* __restrict__ rmean,
                            const float* __restrict__ rvar,
                            _Float16* __restrict__ W1f, float* __restrict__ nA, float* __restrict__ nB)
{
    int t = blockIdx.x * 256 + threadIdx.x;
    if (t < 64 * 64) {
        int l = t & 63, frag = t >> 6;
        int kk = frag & 3, ft = (frag >> 2) & 3, w = frag >> 4;
        int feat = w * 64 + ft * 16 + (l & 15);
        int kbase = kk * 32 + (l >> 4) * 8;
        _Float16 v[8];
#pragma unroll
        for (int i = 0; i < 8; i++) v[i] = (_Float16)W1[(size_t)(kbase + i) * 256 + feat];
        *(fh8*)&W1f[(size_t)t * 8] = *(fh8*)v;
    } else if (t < 64 * 64 + 256) {
        int f = t - 64 * 64;
        float scale = gamma[f] * rsqrtf(rvar[f] + 1e-5f);
        nA[f] = scale;
        nB[f] = (b1[f] - rmean[f]) * scale + beta[f];
    }
}

// ---------------- fused GEMM1 (MFMA) + edge histogram ----------------
__global__ __launch_bounds__(256) void gemm1_hist(
    const float* __restrict__ x, const _Float16* __restrict__ W1f,
    const float* __restrict__ attS1, const float* __restrict__ attD1,
    __half* __restrict__ h1, float* __restrict__ asrc1, float* __restrict__ adst1,
    const int* __restrict__ ei, int* __restrict__ counts)
{
    const int bid = blockIdx.x;
    const int tid = threadIdx.x;
    if (bid >= GB) {
        int e = (bid - GB) * 256 + tid;
        if (e < EE) atomicAdd(&counts[ei[EE + e]], 1);
        return;
    }

    __shared__ _Float16 xh[STRIP][136];
    const int lane = tid & 63;
    const int w    = tid >> 6;            // wave id == head id
    const int base = bid * STRIP;

#pragma unroll
    for (int it = 0; it < 2; ++it) {
        int slot = tid + it * 256;
        int node = slot >> 2;
        int k0   = (slot & 3) * 32;
        int gnode = base + node;
        float4 buf[8];
        if (gnode < NN) {
            const float4* src = (const float4*)(x + (size_t)gnode * 128 + k0);
#pragma unroll
            for (int j = 0; j < 8; j++) buf[j] = src[j];
        } else {
#pragma unroll
            for (int j = 0; j < 8; j++) buf[j] = make_float4(0.f, 0.f, 0.f, 0.f);
        }
        _Float16* dst = &xh[node][k0];
#pragma unroll
        for (int j = 0; j < 8; j++) {
            dst[j * 4 + 0] = (_Float16)buf[j].x;
            dst[j * 4 + 1] = (_Float16)buf[j].y;
            dst[j * 4 + 2] = (_Float16)buf[j].z;
            dst[j * 4 + 3] = (_Float16)buf[j].w;
        }
    }
    __syncthreads();

    fh8 afrag[4][4];
    const fh8* wf = (const fh8*)W1f;
#pragma unroll
    for (int ft = 0; ft < 4; ft++)
#pragma unroll
        for (int kk = 0; kk < 4; kk++)
            afrag[ft][kk] = wf[((w * 4 + ft) * 4 + kk) * 64 + lane];

    const int nrow = lane & 15;
    const int kq   = lane >> 4;

    float attSv[4][4], attDv[4][4];
#pragma unroll
    for (int ft = 0; ft < 4; ft++)
#pragma unroll
        for (int r = 0; r < 4; r++) {
            int feat = w * 64 + ft * 16 + kq * 4 + r;
            attSv[ft][r] = attS1[feat];
            attDv[ft][r] = attD1[feat];
        }

    for (int g = 0; g < STRIP / 16; ++g) {
        fh8 b[4];
#pragma unroll
        for (int kk = 0; kk < 4; kk++)
            b[kk] = *(const fh8*)&xh[g * 16 + nrow][kk * 32 + kq * 8];

        f32x4 d[4];
#pragma unroll
        for (int ft = 0; ft < 4; ft++) {
            d[ft] = (f32x4){0.f, 0.f, 0.f, 0.f};
#pragma unroll
            for (int kk = 0; kk < 4; kk++)
                d[ft] = __builtin_amdgcn_mfma_f32_16x16x32_f16(afrag[ft][kk], b[kk], d[ft], 0, 0, 0);
        }

        int gnode = base + g * 16 + nrow;
        if (gnode < NN) {
            float ps = 0.f, pd = 0.f;
#pragma unroll
            for (int ft = 0; ft < 4; ft++) {
                __half hb[4];
#pragma unroll
                for (int r = 0; r < 4; r++) {
                    float v = d[ft][r];
                    hb[r] = __float2half(v);
                    ps = fmaf(v, attSv[ft][r], ps);
                    pd = fmaf(v, attDv[ft][r], pd);
                }
                *(float2*)&h1[(size_t)gnode * 256 + w * 64 + ft * 16 + kq * 4] = *(float2*)hb;
            }
            ps += __shfl_xor(ps, 16); ps += __shfl_xor(ps, 32);
            pd += __shfl_xor(pd, 16); pd += __shfl_xor(pd, 32);
            if (kq == 0) { asrc1[gnode * 4 + w] = ps; adst1[gnode * 4 + w] = pd; }
        }
    }
}

// ---------------- scans ----------------
__global__ __launch_bounds__(256) void scan1_kernel(const int* __restrict__ counts, int* __restrict__ bsum)
{
    __shared__ int red[256];
    int t = threadIdx.x;
    int i0 = blockIdx.x * 1024 + t * 4;
    int s = 0;
    if (i0 + 3 < NN) {
        int4 v = *(const int4*)&counts[i0];
        s = v.x + v.y + v.z + v.w;
    } else {
#pragma unroll
        for (int j = 0; j < 4; j++) { int i = i0 + j; if (i < NN) s += counts[i]; }
    }
    red[t] = s;
    __syncthreads();
    for (int off = 128; off > 0; off >>= 1) {
        if (t < off) red[t] += red[t + off];
        __syncthreads();
    }
    if (t == 0) bsum[blockIdx.x] = red[0];
}

__global__ void scan2_kernel(const int* __restrict__ bsum, int* __restrict__ bbase, int* __restrict__ offs)
{
    __shared__ int sh[128];
    int t = threadIdx.x;
    int v = (t < NB) ? bsum[t] : 0;
    sh[t] = v;
    __syncthreads();
    for (int off = 1; off < 128; off <<= 1) {
        int u = (t >= off) ? sh[t - off] : 0;
        __syncthreads();
        sh[t] += u;
        __syncthreads();
    }
    if (t < NB) bbase[t] = sh[t] - v;
    if (t == 0) offs[NN] = EE;
}

__global__ __launch_bounds__(256) void scan3_kernel(const int* __restrict__ counts,
                                                    const int* __restrict__ bbase,
                                                    int* __restrict__ offs, int* __restrict__ cursor)
{
    __shared__ int sh[256];
    int t = threadIdx.x;
    int i0 = blockIdx.x * 1024 + t * 4;
    int c[4];
    int s = 0;
#pragma unroll
    for (int j = 0; j < 4; j++) { int i = i0 + j; c[j] = (i < NN) ? counts[i] : 0; s += c[j]; }
    sh[t] = s;
    __syncthreads();
    for (int off = 1; off < 256; off <<= 1) {
        int u = (t >= off) ? sh[t - off] : 0;
        __syncthreads();
        sh[t] += u;
        __syncthreads();
    }
    int run = bbase[blockIdx.x] + sh[t] - s;
    if (i0 + 3 < NN) {
        int4 o;
        o.x = run; run += c[0];
        o.y = run; run += c[1];
        o.z = run; run += c[2];
        o.w = run;
        *(int4*)&offs[i0] = o;
        *(int4*)&cursor[i0] = o;
    } else {
#pragma unroll
        for (int j = 0; j < 4; j++) { int i = i0 + j; if (i < NN) { offs[i] = run; cursor[i] = run; run += c[j]; } }
    }
}

// ---------------- scatter: pure CSR build ----------------
__global__ void scatter_kernel(const int* __restrict__ ei,
                               int* __restrict__ cursor, int* __restrict__ csr_src)
{
    int e = blockIdx.x * 256 + threadIdx.x;
    if (e >= EE) return;
    int s = ei[e], d = ei[EE + e];
    int pos = atomicAdd(&cursor[d], 1);
    csr_src[pos] = s;
}

// ---------------- agg1 + node2 fused: wave per node ----------------
// lane = ep*16 + fl: ep = edge slot (4), fl = 32B feature block (16 x 16 halfs).
// 8 rows in flight per wave (2-unrolled). Epilogue: BN+ELU+W2+att2 in-register.
__global__ __launch_bounds__(256) void agg1_node2(
    const int* __restrict__ offs, const int* __restrict__ csr_src,
    const float* __restrict__ asrc1, const float* __restrict__ adst1,
    const __half* __restrict__ h1,
    const float* __restrict__ nA, const float* __restrict__ nB,
    const float* __restrict__ W2, const float* __restrict__ attS2, const float* __restrict__ attD2,
    float4* __restrict__ pk2)
{
    int wid  = (blockIdx.x * 256 + threadIdx.x) >> 6;
    int lane = threadIdx.x & 63;
    if (wid >= NN) return;
    int lo = offs[wid], hi = offs[wid + 1];
    const int ep   = lane >> 4;    // edge slot
    const int fl   = lane & 15;    // feature block: halfs fl*16 .. fl*16+15
    const int head = fl >> 2;      // head of this lane's 16 feats

    const float adst = adst1[wid * 4 + head];

    float acc[16];
#pragma unroll
    for (int j = 0; j < 16; j++) acc[j] = 0.f;
    float wsum = 0.f;

    for (int base = lo; base < hi; base += 8) {
        int idx0 = base + ep;
        int idx1 = base + 4 + ep;
        bool v0 = idx0 < hi, v1 = idx1 < hi;
        int s0 = csr_src[v0 ? idx0 : lo];
        int s1 = csr_src[v1 ? idx1 : lo];
        float as0 = asrc1[s0 * 4 + head];
        float as1 = asrc1[s1 * 4 + head];
        const uint4* p0 = (const uint4*)(h1 + (size_t)s0 * 256 + fl * 16);
        const uint4* p1 = (const uint4*)(h1 + (size_t)s1 * 256 + fl * 16);
        uint4 r00 = p0[0], r01 = p0[1];
        uint4 r10 = p1[0], r11 = p1[1];
        float w0 = v0 ? expf(lrelu(as0 + adst)) : 0.f;
        float w1 = v1 ? expf(lrelu(as1 + adst)) : 0.f;
        fma8(r00, w0, acc);     fma8(r01, w0, acc + 8);
        fma8(r10, w1, acc);     fma8(r11, w1, acc + 8);
        wsum += w0 + w1;
    }

    // reduce over edge slots (bits 4,5 of lane)
#pragma unroll
    for (int j = 0; j < 16; j++) {
        acc[j] += __shfl_xor(acc[j], 16);
        acc[j] += __shfl_xor(acc[j], 32);
    }
    wsum += __shfl_xor(wsum, 16);
    wsum += __shfl_xor(wsum, 32);

    float inv = 1.f / (wsum + 1e-16f);

    // fused node2: BN affine + ELU + GEMM2(256->2)
    float c0 = 0.f, c1 = 0.f;
#pragma unroll
    for (int j = 0; j < 16; j++) {
        int f = fl * 16 + j;
        float g = acc[j] * inv;
        float u = fmaf(g, nA[f], nB[f]);
        float t = u > 0.f ? u : expm1f(u);
        c0 = fmaf(t, W2[f * 2],     c0);
        c1 = fmaf(t, W2[f * 2 + 1], c1);
    }
    // reduce over 16 feature blocks (bits 0-3)
    c0 += __shfl_xor(c0, 1); c0 += __shfl_xor(c0, 2); c0 += __shfl_xor(c0, 4); c0 += __shfl_xor(c0, 8);
    c1 += __shfl_xor(c1, 1); c1 += __shfl_xor(c1, 2); c1 += __shfl_xor(c1, 4); c1 += __shfl_xor(c1, 8);

    if (lane == 0) {
        float as2 = c0 * attS2[0] + c1 * attS2[1];
        float ad2 = c0 * attD2[0] + c1 * attD2[1];
        pk2[wid] = make_float4(as2, ad2, c0, c1);
    }
}

// ---------------- agg2: 8 lanes per node + fused bias/log_softmax ----------------
__global__ __launch_bounds__(256) void agg2_kernel(
    const int* __restrict__ offs, const int* __restrict__ csr_src,
    const float4* __restrict__ pk2, const float* __restrict__ b2,
    float* __restrict__ out)
{
    int wid  = (blockIdx.x * 256 + threadIdx.x) >> 6;
    int lane = threadIdx.x & 63;
    int grp  = lane >> 3;
    int sub  = lane & 7;
    int n = wid * 8 + grp;
    if (n >= NN) return;
    int lo = offs[n], hi = offs[n + 1];
    float ad = pk2[n].y;

    float n0 = 0.f, n1 = 0.f, ws = 0.f;
    for (int i = lo + sub; i < hi; i += 8) {
        int s = csr_src[i];
        float4 p = pk2[s];
        float w = expf(lrelu(p.x + ad));
        n0 = fmaf(w, p.z, n0);
        n1 = fmaf(w, p.w, n1);
        ws += w;
    }
    n0 += __shfl_xor(n0, 1); n0 += __shfl_xor(n0, 2); n0 += __shfl_xor(n0, 4);
    n1 += __shfl_xor(n1, 1); n1 += __shfl_xor(n1, 2); n1 += __shfl_xor(n1, 4);
    ws += __shfl_xor(ws, 1); ws += __shfl_xor(ws, 2); ws += __shfl_xor(ws, 4);

    if (sub == 0) {
        float inv = 1.f / (ws + 1e-16f);
        float v0 = n0 * inv + b2[0];
        float v1 = n1 * inv + b2[1];
        float m = fmaxf(v0, v1);
        float lse = m + log1pf(expf(fminf(v0, v1) - m));
        *(float2*)&out[(size_t)n * 2] = make_float2(v0 - lse, v1 - lse);
    }
}

extern "C" void kernel_launch(void* const* d_in, const int* in_sizes, int n_in,
                              void* d_out, int out_size, void* d_ws, size_t ws_size,
                              hipStream_t stream)
{
    const float* x     = (const float*)d_in[0];
    const int*   ei    = (const int*)d_in[1];
    const float* W1    = (const float*)d_in[2];
    const float* attS1 = (const float*)d_in[3];
    const float* attD1 = (const float*)d_in[4];
    const float* b1    = (const float*)d_in[5];
    const float* gamma = (const float*)d_in[6];
    const float* beta  = (const float*)d_in[7];
    const float* rmean = (const float*)d_in[8];
    const float* rvar  = (const float*)d_in[9];
    const float* W2    = (const float*)d_in[10];
    const float* attS2 = (const float*)d_in[11];
    const float* attD2 = (const float*)d_in[12];
    const float* b2    = (const float*)d_in[13];
    float* out = (float*)d_out;

    float* f = (float*)d_ws;
    __half* h1    = (__half*)f;                  // N*256 halfs = N*128 floats
    float* asrc1  = f + (size_t)NN * 128;        // N*4
    float* adst1  = asrc1 + (size_t)NN * 4;      // N*4
    _Float16* W1f = (_Float16*)(adst1 + (size_t)NN * 4);  // 32768 halfs = 16384 floats
    float* nA     = adst1 + (size_t)NN * 4 + 16384;       // 256
    float* nB     = nA + 256;                    // 256
    float4* pk2   = (float4*)(nB + 256);         // N float4
    int* counts   = (int*)(nB + 256 + (size_t)NN * 4);    // N [zeroed]
    int* offs     = counts + NN;                 // N+1
    int* cursor   = offs + (NN + 1);             // N
    int* bsum     = cursor + NN;                 // NB
    int* bbase    = bsum + NB;                   // NB
    int* csr_src  = bbase + NB;                  // E

    hipMemsetAsync(counts, 0, (size_t)NN * sizeof(int), stream);

    prep_kernel<<<18, 256, 0, stream>>>(W1, b1, gamma, beta, rmean, rvar, W1f, nA, nB);

    gemm1_hist<<<GB + HB, 256, 0, stream>>>(x, W1f, attS1, attD1, h1, asrc1, adst1, ei, counts);

    scan1_kernel<<<NB, 256, 0, stream>>>(counts, bsum);
    scan2_kernel<<<1, 128, 0, stream>>>(bsum, bbase, offs);
    scan3_kernel<<<NB, 256, 0, stream>>>(counts, bbase, offs, cursor);

    scatter_kernel<<<HB, 256, 0, stream>>>(ei, cursor, csr_src);

    agg1_node2<<<NN / 4, 256, 0, stream>>>(offs, csr_src, asrc1, adst1, h1,
                                           nA, nB, W2, attS2, attD2, pk2);

    agg2_kernel<<<(NN + 31) / 32, 256, 0, stream>>>(offs, csr_src, pk2, b2, out);
}

// Round 8
// 344.492 us; speedup vs baseline: 2.2874x; 2.2874x over previous
//
#include <hip/hip_runtime.h>
#include <hip/hip_fp16.h>
#include <math.h>

#define NN 100000
#define EE 1600000
#define NEG 0.2f
#define NB 98     // ceil(NN/1024) scan blocks
#define STRIP 128 // nodes per gemm1 block
#define GB 782    // gemm blocks = ceil(NN/STRIP)
#define HB 6250   // hist blocks = ceil(EE/256)

typedef _Float16 fh8 __attribute__((ext_vector_type(8)));
typedef float f32x4 __attribute__((ext_vector_type(4)));

__device__ __forceinline__ float lrelu(float v) { return v > 0.f ? v : NEG * v; }

__device__ __forceinline__ void fma8(const uint4& r, float w, float* acc)
{
    float2 f0 = __half22float2(*(const __half2*)&r.x);
    float2 f1 = __half22float2(*(const __half2*)&r.y);
    float2 f2 = __half22float2(*(const __half2*)&r.z);
    float2 f3 = __half22float2(*(const __half2*)&r.w);
    acc[0] = fmaf(w, f0.x, acc[0]); acc[1] = fmaf(w, f0.y, acc[1]);
    acc[2] = fmaf(w, f1.x, acc[2]); acc[3] = fmaf(w, f1.y, acc[3]);
    acc[4] = fmaf(w, f2.x, acc[4]); acc[5] = fmaf(w, f2.y, acc[5]);
    acc[6] = fmaf(w, f3.x, acc[6]); acc[7] = fmaf(w, f3.y, acc[7]);
}

// ---------------- prep: pack W1 (MFMA A-frag order) + BN affine + zero counts ----------------
__global__ __launch_bounds__(256) void prep_kernel(
    const float* __restrict__ W1,
    const float* __restrict__ b1, const float* __restrict__ gamma,
    const float* __restrict__ beta, const float* __restrict__ rmean,
    const float* __restrict__ rvar,
    _Float16* __restrict__ W1f, float* __restrict__ nA, float* __restrict__ nB,
    int* __restrict__ counts)
{
    int t = blockIdx.x * 256 + threadIdx.x;   // grid = 128 blocks -> 32768 threads
    if (t < 64 * 64) {
        int l = t & 63, frag = t >> 6;
        int kk = frag & 3, ft = (frag >> 2) & 3, w = frag >> 4;
        int feat = w * 64 + ft * 16 + (l & 15);
        int kbase = kk * 32 + (l >> 4) * 8;
        _Float16 v[8];
#pragma unroll
        for (int i = 0; i < 8; i++) v[i] = (_Float16)W1[(size_t)(kbase + i) * 256 + feat];
        *(fh8*)&W1f[(size_t)t * 8] = *(fh8*)v;
    } else if (t < 64 * 64 + 256) {
        int f = t - 64 * 64;
        float scale = gamma[f] * rsqrtf(rvar[f] + 1e-5f);
        nA[f] = scale;
        nB[f] = (b1[f] - rmean[f]) * scale + beta[f];
    }
    for (int i = t; i < NN; i += 128 * 256) counts[i] = 0;
}

// ---------------- fused GEMM1 (MFMA) + edge histogram ----------------
__global__ __launch_bounds__(256) void gemm1_hist(
    const float* __restrict__ x, const _Float16* __restrict__ W1f,
    const float* __restrict__ attS1, const float* __restrict__ attD1,
    __half* __restrict__ h1, float* __restrict__ asrc1, float* __restrict__ adst1,
    const int* __restrict__ ei, int* __restrict__ counts)
{
    const int bid = blockIdx.x;
    const int tid = threadIdx.x;
    if (bid >= GB) {
        int e = (bid - GB) * 256 + tid;
        if (e < EE) atomicAdd(&counts[ei[EE + e]], 1);
        return;
    }

    __shared__ _Float16 xh[STRIP][136];
    const int lane = tid & 63;
    const int w    = tid >> 6;            // wave id == head id
    const int base = bid * STRIP;

#pragma unroll
    for (int it = 0; it < 2; ++it) {
        int slot = tid + it * 256;
        int node = slot >> 2;
        int k0   = (slot & 3) * 32;
        int gnode = base + node;
        float4 buf[8];
        if (gnode < NN) {
            const float4* src = (const float4*)(x + (size_t)gnode * 128 + k0);
#pragma unroll
            for (int j = 0; j < 8; j++) buf[j] = src[j];
        } else {
#pragma unroll
            for (int j = 0; j < 8; j++) buf[j] = make_float4(0.f, 0.f, 0.f, 0.f);
        }
        _Float16* dst = &xh[node][k0];
#pragma unroll
        for (int j = 0; j < 8; j++) {
            dst[j * 4 + 0] = (_Float16)buf[j].x;
            dst[j * 4 + 1] = (_Float16)buf[j].y;
            dst[j * 4 + 2] = (_Float16)buf[j].z;
            dst[j * 4 + 3] = (_Float16)buf[j].w;
        }
    }
    __syncthreads();

    fh8 afrag[4][4];
    const fh8* wf = (const fh8*)W1f;
#pragma unroll
    for (int ft = 0; ft < 4; ft++)
#pragma unroll
        for (int kk = 0; kk < 4; kk++)
            afrag[ft][kk] = wf[((w * 4 + ft) * 4 + kk) * 64 + lane];

    const int nrow = lane & 15;
    const int kq   = lane >> 4;

    float attSv[4][4], attDv[4][4];
#pragma unroll
    for (int ft = 0; ft < 4; ft++)
#pragma unroll
        for (int r = 0; r < 4; r++) {
            int feat = w * 64 + ft * 16 + kq * 4 + r;
            attSv[ft][r] = attS1[feat];
            attDv[ft][r] = attD1[feat];
        }

    for (int g = 0; g < STRIP / 16; ++g) {
        fh8 b[4];
#pragma unroll
        for (int kk = 0; kk < 4; kk++)
            b[kk] = *(const fh8*)&xh[g * 16 + nrow][kk * 32 + kq * 8];

        f32x4 d[4];
#pragma unroll
        for (int ft = 0; ft < 4; ft++) {
            d[ft] = (f32x4){0.f, 0.f, 0.f, 0.f};
#pragma unroll
            for (int kk = 0; kk < 4; kk++)
                d[ft] = __builtin_amdgcn_mfma_f32_16x16x32_f16(afrag[ft][kk], b[kk], d[ft], 0, 0, 0);
        }

        int gnode = base + g * 16 + nrow;
        if (gnode < NN) {
            float ps = 0.f, pd = 0.f;
#pragma unroll
            for (int ft = 0; ft < 4; ft++) {
                __half hb[4];
#pragma unroll
                for (int r = 0; r < 4; r++) {
                    float v = d[ft][r];
                    hb[r] = __float2half(v);
                    ps = fmaf(v, attSv[ft][r], ps);
                    pd = fmaf(v, attDv[ft][r], pd);
                }
                *(float2*)&h1[(size_t)gnode * 256 + w * 64 + ft * 16 + kq * 4] = *(float2*)hb;
            }
            ps += __shfl_xor(ps, 16); ps += __shfl_xor(ps, 32);
            pd += __shfl_xor(pd, 16); pd += __shfl_xor(pd, 32);
            if (kq == 0) { asrc1[gnode * 4 + w] = ps; adst1[gnode * 4 + w] = pd; }
        }
    }
}

// ---------------- scans ----------------
__global__ __launch_bounds__(256) void scan1_kernel(const int* __restrict__ counts, int* __restrict__ bsum)
{
    __shared__ int red[256];
    int t = threadIdx.x;
    int i0 = blockIdx.x * 1024 + t * 4;
    int s = 0;
    if (i0 + 3 < NN) {
        int4 v = *(const int4*)&counts[i0];
        s = v.x + v.y + v.z + v.w;
    } else {
#pragma unroll
        for (int j = 0; j < 4; j++) { int i = i0 + j; if (i < NN) s += counts[i]; }
    }
    red[t] = s;
    __syncthreads();
    for (int off = 128; off > 0; off >>= 1) {
        if (t < off) red[t] += red[t + off];
        __syncthreads();
    }
    if (t == 0) bsum[blockIdx.x] = red[0];
}

__global__ void scan2_kernel(const int* __restrict__ bsum, int* __restrict__ bbase, int* __restrict__ offs)
{
    __shared__ int sh[128];
    int t = threadIdx.x;
    int v = (t < NB) ? bsum[t] : 0;
    sh[t] = v;
    __syncthreads();
    for (int off = 1; off < 128; off <<= 1) {
        int u = (t >= off) ? sh[t - off] : 0;
        __syncthreads();
        sh[t] += u;
        __syncthreads();
    }
    if (t < NB) bbase[t] = sh[t] - v;
    if (t == 0) offs[NN] = EE;
}

__global__ __launch_bounds__(256) void scan3_kernel(const int* __restrict__ counts,
                                                    const int* __restrict__ bbase,
                                                    int* __restrict__ offs, int* __restrict__ cursor)
{
    __shared__ int sh[256];
    int t = threadIdx.x;
    int i0 = blockIdx.x * 1024 + t * 4;
    int c[4];
    int s = 0;
#pragma unroll
    for (int j = 0; j < 4; j++) { int i = i0 + j; c[j] = (i < NN) ? counts[i] : 0; s += c[j]; }
    sh[t] = s;
    __syncthreads();
    for (int off = 1; off < 256; off <<= 1) {
        int u = (t >= off) ? sh[t - off] : 0;
        __syncthreads();
        sh[t] += u;
        __syncthreads();
    }
    int run = bbase[blockIdx.x] + sh[t] - s;
    if (i0 + 3 < NN) {
        int4 o;
        o.x = run; run += c[0];
        o.y = run; run += c[1];
        o.z = run; run += c[2];
        o.w = run;
        *(int4*)&offs[i0] = o;
        *(int4*)&cursor[i0] = o;
    } else {
#pragma unroll
        for (int j = 0; j < 4; j++) { int i = i0 + j; if (i < NN) { offs[i] = run; cursor[i] = run; run += c[j]; } }
    }
}

// ---------------- scatter: CSR build + fused edge weights ----------------
__global__ void scatter_kernel(const int* __restrict__ ei,
                               const float* __restrict__ asrc1, const float* __restrict__ adst1,
                               int* __restrict__ cursor, int* __restrict__ csr_src,
                               float* __restrict__ ewp)
{
    int e = blockIdx.x * 256 + threadIdx.x;
    if (e >= EE) return;
    int s = ei[e], d = ei[EE + e];
    int pos = atomicAdd(&cursor[d], 1);
    csr_src[pos] = s;
    float4 as = *(const float4*)&asrc1[(size_t)s * 4];
    float4 ad = *(const float4*)&adst1[(size_t)d * 4];
    float4 w;
    w.x = expf(lrelu(as.x + ad.x));
    w.y = expf(lrelu(as.y + ad.y));
    w.z = expf(lrelu(as.z + ad.z));
    w.w = expf(lrelu(as.w + ad.w));
    *(float4*)&ewp[(size_t)pos * 4] = w;
}

// ---------------- layer-1 aggregation: one wave per node, 2 edges/iter + 2x unroll ----------------
// (R6-proven inner loop; do not restructure)
__global__ __launch_bounds__(256) void agg1_kernel(
    const int* __restrict__ offs, const int* __restrict__ csr_src,
    const float* __restrict__ ewp, const __half* __restrict__ h1,
    float* __restrict__ g1)
{
    int wid  = (blockIdx.x * 256 + threadIdx.x) >> 6;
    int lane = threadIdx.x & 63;
    if (wid >= NN) return;
    int lo = offs[wid], hi = offs[wid + 1];
    const int ep   = lane >> 5;
    const int fl   = lane & 31;
    const int head = fl >> 3;

    float acc[8] = {0.f, 0.f, 0.f, 0.f, 0.f, 0.f, 0.f, 0.f};
    float wsum = 0.f;

    int base = lo;
    for (; base + 3 < hi; base += 4) {
        int idx0 = base + ep;
        int idx1 = base + 2 + ep;
        int s0 = csr_src[idx0];
        int s1 = csr_src[idx1];
        float w0 = ewp[(size_t)idx0 * 4 + head];
        float w1 = ewp[(size_t)idx1 * 4 + head];
        uint4 r0 = *(const uint4*)(h1 + (size_t)s0 * 256 + fl * 8);
        uint4 r1 = *(const uint4*)(h1 + (size_t)s1 * 256 + fl * 8);
        fma8(r0, w0, acc);
        fma8(r1, w1, acc);
        wsum += w0 + w1;
    }
    for (; base < hi; base += 2) {
        int idx = base + ep;
        float w = 0.f;
        uint4 r = make_uint4(0, 0, 0, 0);
        if (idx < hi) {
            int s = csr_src[idx];
            w = ewp[(size_t)idx * 4 + head];
            r = *(const uint4*)(h1 + (size_t)s * 256 + fl * 8);
        }
        fma8(r, w, acc);
        wsum += w;
    }

#pragma unroll
    for (int j = 0; j < 8; j++) acc[j] += __shfl_xor(acc[j], 32);
    wsum += __shfl_xor(wsum, 32);

    if (lane < 32) {
        float inv = 1.f / (wsum + 1e-16f);
        *(float4*)&g1[(size_t)wid * 256 + fl * 8]     = make_float4(acc[0] * inv, acc[1] * inv, acc[2] * inv, acc[3] * inv);
        *(float4*)&g1[(size_t)wid * 256 + fl * 8 + 4] = make_float4(acc[4] * inv, acc[5] * inv, acc[6] * inv, acc[7] * inv);
    }
}

// ---------------- node2: BN(affine) + ELU + GEMM2(256->2) + att2, packed output ----------------
__global__ __launch_bounds__(256) void node2_kernel(
    const float* __restrict__ g1,
    const float* __restrict__ nA, const float* __restrict__ nB,
    const float* __restrict__ W2, const float* __restrict__ attS2, const float* __restrict__ attD2,
    float4* __restrict__ pk2)
{
    int n    = blockIdx.x * 4 + (threadIdx.x >> 6);
    int lane = threadIdx.x & 63;
    if (n >= NN) return;
    int f4 = lane * 4;
    float4 v  = *(const float4*)&g1[(size_t)n * 256 + f4];
    float4 na = *(const float4*)&nA[f4];
    float4 nb = *(const float4*)&nB[f4];
    float va[4] = {v.x, v.y, v.z, v.w};
    float naa[4] = {na.x, na.y, na.z, na.w};
    float nba[4] = {nb.x, nb.y, nb.z, nb.w};
    float t[4];
#pragma unroll
    for (int j = 0; j < 4; j++) {
        float u = fmaf(va[j], naa[j], nba[j]);
        t[j] = u > 0.f ? u : expm1f(u);
    }
    float4 w01 = *(const float4*)&W2[(size_t)f4 * 2];
    float4 w23 = *(const float4*)&W2[(size_t)f4 * 2 + 4];
    float c0 = t[0] * w01.x + t[1] * w01.z + t[2] * w23.x + t[3] * w23.z;
    float c1 = t[0] * w01.y + t[1] * w01.w + t[2] * w23.y + t[3] * w23.w;
    for (int off = 1; off < 64; off <<= 1) {
        c0 += __shfl_xor(c0, off);
        c1 += __shfl_xor(c1, off);
    }
    if (lane == 0) {
        float as2 = c0 * attS2[0] + c1 * attS2[1];
        float ad2 = c0 * attD2[0] + c1 * attD2[1];
        pk2[n] = make_float4(as2, ad2, c0, c1);
    }
}

// ---------------- agg2: 8 lanes per node, 16B pk2 gather + fused log_softmax ----------------
__global__ __launch_bounds__(256) void agg2_kernel(
    const int* __restrict__ offs, const int* __restrict__ csr_src,
    const float4* __restrict__ pk2, const float* __restrict__ b2,
    float* __restrict__ out)
{
    int wid  = (blockIdx.x * 256 + threadIdx.x) >> 6;
    int lane = threadIdx.x & 63;
    int grp  = lane >> 3;
    int sub  = lane & 7;
    int n = wid * 8 + grp;
    if (n >= NN) return;
    int lo = offs[n], hi = offs[n + 1];
    float ad = pk2[n].y;

    float n0 = 0.f, n1 = 0.f, ws = 0.f;
    for (int i = lo + sub; i < hi; i += 8) {
        int s = csr_src[i];
        float4 p = pk2[s];
        float w = expf(lrelu(p.x + ad));
        n0 = fmaf(w, p.z, n0);
        n1 = fmaf(w, p.w, n1);
        ws += w;
    }
    n0 += __shfl_xor(n0, 1); n0 += __shfl_xor(n0, 2); n0 += __shfl_xor(n0, 4);
    n1 += __shfl_xor(n1, 1); n1 += __shfl_xor(n1, 2); n1 += __shfl_xor(n1, 4);
    ws += __shfl_xor(ws, 1); ws += __shfl_xor(ws, 2); ws += __shfl_xor(ws, 4);

    if (sub == 0) {
        float inv = 1.f / (ws + 1e-16f);
        float v0 = n0 * inv + b2[0];
        float v1 = n1 * inv + b2[1];
        float m = fmaxf(v0, v1);
        float lse = m + log1pf(expf(fminf(v0, v1) - m));
        *(float2*)&out[(size_t)n * 2] = make_float2(v0 - lse, v1 - lse);
    }
}

extern "C" void kernel_launch(void* const* d_in, const int* in_sizes, int n_in,
                              void* d_out, int out_size, void* d_ws, size_t ws_size,
                              hipStream_t stream)
{
    const float* x     = (const float*)d_in[0];
    const int*   ei    = (const int*)d_in[1];
    const float* W1    = (const float*)d_in[2];
    const float* attS1 = (const float*)d_in[3];
    const float* attD1 = (const float*)d_in[4];
    const float* b1    = (const float*)d_in[5];
    const float* gamma = (const float*)d_in[6];
    const float* beta  = (const float*)d_in[7];
    const float* rmean = (const float*)d_in[8];
    const float* rvar  = (const float*)d_in[9];
    const float* W2    = (const float*)d_in[10];
    const float* attS2 = (const float*)d_in[11];
    const float* attD2 = (const float*)d_in[12];
    const float* b2    = (const float*)d_in[13];
    float* out = (float*)d_out;

    float* f = (float*)d_ws;
    __half* h1    = (__half*)f;                  // N*256 halfs = N*128 floats
    float* asrc1  = f + (size_t)NN * 128;        // N*4
    float* adst1  = asrc1 + (size_t)NN * 4;      // N*4
    _Float16* W1f = (_Float16*)(adst1 + (size_t)NN * 4);  // 32768 halfs = 16384 floats
    float* nA     = adst1 + (size_t)NN * 4 + 16384;       // 256
    float* nB     = nA + 256;                    // 256
    float4* pk2   = (float4*)(nB + 256);         // N float4
    float* g1     = nB + 256 + (size_t)NN * 4;   // N*256
    float* ewp    = g1 + (size_t)NN * 256;       // E*4
    int* counts   = (int*)(ewp + (size_t)EE * 4); // N [zeroed in prep]
    int* offs     = counts + NN;                 // N+1
    int* cursor   = offs + (NN + 1);             // N
    int* bsum     = cursor + NN;                 // NB
    int* bbase    = bsum + NB;                   // NB
    int* csr_src  = bbase + NB;                  // E

    prep_kernel<<<128, 256, 0, stream>>>(W1, b1, gamma, beta, rmean, rvar, W1f, nA, nB, counts);

    gemm1_hist<<<GB + HB, 256, 0, stream>>>(x, W1f, attS1, attD1, h1, asrc1, adst1, ei, counts);

    scan1_kernel<<<NB, 256, 0, stream>>>(counts, bsum);
    scan2_kernel<<<1, 128, 0, stream>>>(bsum, bbase, offs);
    scan3_kernel<<<NB, 256, 0, stream>>>(counts, bbase, offs, cursor);

    scatter_kernel<<<HB, 256, 0, stream>>>(ei, asrc1, adst1, cursor, csr_src, ewp);

    agg1_kernel<<<(NN + 3) / 4, 256, 0, stream>>>(offs, csr_src, ewp, h1, g1);

    node2_kernel<<<(NN + 3) / 4, 256, 0, stream>>>(g1, nA, nB, W2, attS2, attD2, pk2);

    agg2_kernel<<<(NN + 31) / 32, 256, 0, stream>>>(offs, csr_src, pk2, b2, out);
}

// Round 9
// 311.319 us; speedup vs baseline: 2.5312x; 1.1066x over previous
//
#include <hip/hip_runtime.h>
#include <hip/hip_fp16.h>
#include <math.h>

#define NN 100000
#define EE 1600000
#define NEG 0.2f
#define NB 98     // ceil(NN/1024) scan blocks
#define STRIP 128 // nodes per gemm1 block
#define GB 782    // gemm blocks = ceil(NN/STRIP)
#define HB 6250   // hist blocks = ceil(EE/256)

typedef _Float16 fh8 __attribute__((ext_vector_type(8)));
typedef float f32x4 __attribute__((ext_vector_type(4)));

__device__ __forceinline__ float lrelu(float v) { return v > 0.f ? v : NEG * v; }

__device__ __forceinline__ void fma8(const uint4& r, float w, float* acc)
{
    float2 f0 = __half22float2(*(const __half2*)&r.x);
    float2 f1 = __half22float2(*(const __half2*)&r.y);
    float2 f2 = __half22float2(*(const __half2*)&r.z);
    float2 f3 = __half22float2(*(const __half2*)&r.w);
    acc[0] = fmaf(w, f0.x, acc[0]); acc[1] = fmaf(w, f0.y, acc[1]);
    acc[2] = fmaf(w, f1.x, acc[2]); acc[3] = fmaf(w, f1.y, acc[3]);
    acc[4] = fmaf(w, f2.x, acc[4]); acc[5] = fmaf(w, f2.y, acc[5]);
    acc[6] = fmaf(w, f3.x, acc[6]); acc[7] = fmaf(w, f3.y, acc[7]);
}

// extract head-h weight from packed entry {src, w01(half2), w23(half2), pad}
__device__ __forceinline__ float ewgt(const int4& e, int head)
{
    uint p = (head < 2) ? (uint)e.y : (uint)e.z;
    float2 f = __half22float2(*(const __half2*)&p);
    return (head & 1) ? f.y : f.x;
}

// ---------------- prep: pack W1 (MFMA A-frag order) + BN affine + zero counts ----------------
__global__ __launch_bounds__(256) void prep_kernel(
    const float* __restrict__ W1,
    const float* __restrict__ b1, const float* __restrict__ gamma,
    const float* __restrict__ beta, const float* __restrict__ rmean,
    const float* __restrict__ rvar,
    _Float16* __restrict__ W1f, float* __restrict__ nA, float* __restrict__ nB,
    int* __restrict__ counts)
{
    int t = blockIdx.x * 256 + threadIdx.x;   // grid = 128 blocks
    if (t < 64 * 64) {
        int l = t & 63, frag = t >> 6;
        int kk = frag & 3, ft = (frag >> 2) & 3, w = frag >> 4;
        int feat = w * 64 + ft * 16 + (l & 15);
        int kbase = kk * 32 + (l >> 4) * 8;
        _Float16 v[8];
#pragma unroll
        for (int i = 0; i < 8; i++) v[i] = (_Float16)W1[(size_t)(kbase + i) * 256 + feat];
        *(fh8*)&W1f[(size_t)t * 8] = *(fh8*)v;
    } else if (t < 64 * 64 + 256) {
        int f = t - 64 * 64;
        float scale = gamma[f] * rsqrtf(rvar[f] + 1e-5f);
        nA[f] = scale;
        nB[f] = (b1[f] - rmean[f]) * scale + beta[f];
    }
    for (int i = t; i < NN; i += 128 * 256) counts[i] = 0;
}

// ---------------- fused GEMM1 (MFMA) + edge histogram ----------------
__global__ __launch_bounds__(256) void gemm1_hist(
    const float* __restrict__ x, const _Float16* __restrict__ W1f,
    const float* __restrict__ attS1, const float* __restrict__ attD1,
    __half* __restrict__ h1, float* __restrict__ asrc1, float* __restrict__ adst1,
    const int* __restrict__ ei, int* __restrict__ counts)
{
    const int bid = blockIdx.x;
    const int tid = threadIdx.x;
    if (bid >= GB) {
        int e = (bid - GB) * 256 + tid;
        if (e < EE) atomicAdd(&counts[ei[EE + e]], 1);
        return;
    }

    __shared__ _Float16 xh[STRIP][136];
    const int lane = tid & 63;
    const int w    = tid >> 6;            // wave id == head id
    const int base = bid * STRIP;

#pragma unroll
    for (int it = 0; it < 2; ++it) {
        int slot = tid + it * 256;
        int node = slot >> 2;
        int k0   = (slot & 3) * 32;
        int gnode = base + node;
        float4 buf[8];
        if (gnode < NN) {
            const float4* src = (const float4*)(x + (size_t)gnode * 128 + k0);
#pragma unroll
            for (int j = 0; j < 8; j++) buf[j] = src[j];
        } else {
#pragma unroll
            for (int j = 0; j < 8; j++) buf[j] = make_float4(0.f, 0.f, 0.f, 0.f);
        }
        _Float16* dst = &xh[node][k0];
#pragma unroll
        for (int j = 0; j < 8; j++) {
            dst[j * 4 + 0] = (_Float16)buf[j].x;
            dst[j * 4 + 1] = (_Float16)buf[j].y;
            dst[j * 4 + 2] = (_Float16)buf[j].z;
            dst[j * 4 + 3] = (_Float16)buf[j].w;
        }
    }
    __syncthreads();

    fh8 afrag[4][4];
    const fh8* wf = (const fh8*)W1f;
#pragma unroll
    for (int ft = 0; ft < 4; ft++)
#pragma unroll
        for (int kk = 0; kk < 4; kk++)
            afrag[ft][kk] = wf[((w * 4 + ft) * 4 + kk) * 64 + lane];

    const int nrow = lane & 15;
    const int kq   = lane >> 4;

    float attSv[4][4], attDv[4][4];
#pragma unroll
    for (int ft = 0; ft < 4; ft++)
#pragma unroll
        for (int r = 0; r < 4; r++) {
            int feat = w * 64 + ft * 16 + kq * 4 + r;
            attSv[ft][r] = attS1[feat];
            attDv[ft][r] = attD1[feat];
        }

    for (int g = 0; g < STRIP / 16; ++g) {
        fh8 b[4];
#pragma unroll
        for (int kk = 0; kk < 4; kk++)
            b[kk] = *(const fh8*)&xh[g * 16 + nrow][kk * 32 + kq * 8];

        f32x4 d[4];
#pragma unroll
        for (int ft = 0; ft < 4; ft++) {
            d[ft] = (f32x4){0.f, 0.f, 0.f, 0.f};
#pragma unroll
            for (int kk = 0; kk < 4; kk++)
                d[ft] = __builtin_amdgcn_mfma_f32_16x16x32_f16(afrag[ft][kk], b[kk], d[ft], 0, 0, 0);
        }

        int gnode = base + g * 16 + nrow;
        if (gnode < NN) {
            float ps = 0.f, pd = 0.f;
#pragma unroll
            for (int ft = 0; ft < 4; ft++) {
                __half hb[4];
#pragma unroll
                for (int r = 0; r < 4; r++) {
                    float v = d[ft][r];
                    hb[r] = __float2half(v);
                    ps = fmaf(v, attSv[ft][r], ps);
                    pd = fmaf(v, attDv[ft][r], pd);
                }
                *(float2*)&h1[(size_t)gnode * 256 + w * 64 + ft * 16 + kq * 4] = *(float2*)hb;
            }
            ps += __shfl_xor(ps, 16); ps += __shfl_xor(ps, 32);
            pd += __shfl_xor(pd, 16); pd += __shfl_xor(pd, 32);
            if (kq == 0) { asrc1[gnode * 4 + w] = ps; adst1[gnode * 4 + w] = pd; }
        }
    }
}

// ---------------- scans ----------------
__global__ __launch_bounds__(256) void scan1_kernel(const int* __restrict__ counts, int* __restrict__ bsum)
{
    __shared__ int red[256];
    int t = threadIdx.x;
    int i0 = blockIdx.x * 1024 + t * 4;
    int s = 0;
    if (i0 + 3 < NN) {
        int4 v = *(const int4*)&counts[i0];
        s = v.x + v.y + v.z + v.w;
    } else {
#pragma unroll
        for (int j = 0; j < 4; j++) { int i = i0 + j; if (i < NN) s += counts[i]; }
    }
    red[t] = s;
    __syncthreads();
    for (int off = 128; off > 0; off >>= 1) {
        if (t < off) red[t] += red[t + off];
        __syncthreads();
    }
    if (t == 0) bsum[blockIdx.x] = red[0];
}

__global__ void scan2_kernel(const int* __restrict__ bsum, int* __restrict__ bbase, int* __restrict__ offs)
{
    __shared__ int sh[128];
    int t = threadIdx.x;
    int v = (t < NB) ? bsum[t] : 0;
    sh[t] = v;
    __syncthreads();
    for (int off = 1; off < 128; off <<= 1) {
        int u = (t >= off) ? sh[t - off] : 0;
        __syncthreads();
        sh[t] += u;
        __syncthreads();
    }
    if (t < NB) bbase[t] = sh[t] - v;
    if (t == 0) offs[NN] = EE;
}

__global__ __launch_bounds__(256) void scan3_kernel(const int* __restrict__ counts,
                                                    const int* __restrict__ bbase,
                                                    int* __restrict__ offs, int* __restrict__ cursor)
{
    __shared__ int sh[256];
    int t = threadIdx.x;
    int i0 = blockIdx.x * 1024 + t * 4;
    int c[4];
    int s = 0;
#pragma unroll
    for (int j = 0; j < 4; j++) { int i = i0 + j; c[j] = (i < NN) ? counts[i] : 0; s += c[j]; }
    sh[t] = s;
    __syncthreads();
    for (int off = 1; off < 256; off <<= 1) {
        int u = (t >= off) ? sh[t - off] : 0;
        __syncthreads();
        sh[t] += u;
        __syncthreads();
    }
    int run = bbase[blockIdx.x] + sh[t] - s;
    if (i0 + 3 < NN) {
        int4 o;
        o.x = run; run += c[0];
        o.y = run; run += c[1];
        o.z = run; run += c[2];
        o.w = run;
        *(int4*)&offs[i0] = o;
        *(int4*)&cursor[i0] = o;
    } else {
#pragma unroll
        for (int j = 0; j < 4; j++) { int i = i0 + j; if (i < NN) { offs[i] = run; cursor[i] = run; run += c[j]; } }
    }
}

// ---------------- scatter: CSR build, packed 16B entry {src, w as 4xfp16} ----------------
__global__ void scatter_kernel(const int* __restrict__ ei,
                               const float* __restrict__ asrc1, const float* __restrict__ adst1,
                               int* __restrict__ cursor, int4* __restrict__ csr)
{
    int e = blockIdx.x * 256 + threadIdx.x;
    if (e >= EE) return;
    int s = ei[e], d = ei[EE + e];
    int pos = atomicAdd(&cursor[d], 1);
    float4 as = *(const float4*)&asrc1[(size_t)s * 4];
    float4 ad = *(const float4*)&adst1[(size_t)d * 4];
    __half2 w01 = __floats2half2_rn(expf(lrelu(as.x + ad.x)), expf(lrelu(as.y + ad.y)));
    __half2 w23 = __floats2half2_rn(expf(lrelu(as.z + ad.z)), expf(lrelu(as.w + ad.w)));
    int4 ent;
    ent.x = s;
    ent.y = *(const int*)&w01;
    ent.z = *(const int*)&w23;
    ent.w = 0;
    csr[pos] = ent;
}

// ---------------- agg1 + node2-epilogue: one wave per node ----------------
// Inner loop identical memory pattern to R6-proven agg1 (2 slots x 2 unroll, 16B rows,
// broadcast metadata). Epilogue after the xor-32 merge: all 64 lanes hold the full
// 256-feat vector (8 feats/lane) -> BN+ELU+W2 in-register, write packed pk2 only.
__global__ __launch_bounds__(256) void agg1_node2(
    const int* __restrict__ offs, const int4* __restrict__ csr,
    const __half* __restrict__ h1,
    const float* __restrict__ nA, const float* __restrict__ nB,
    const float* __restrict__ W2, const float* __restrict__ attS2, const float* __restrict__ attD2,
    float4* __restrict__ pk2)
{
    int wid  = (blockIdx.x * 256 + threadIdx.x) >> 6;
    int lane = threadIdx.x & 63;
    if (wid >= NN) return;
    int lo = offs[wid], hi = offs[wid + 1];
    const int ep   = lane >> 5;
    const int fl   = lane & 31;
    const int head = fl >> 3;

    float acc[8] = {0.f, 0.f, 0.f, 0.f, 0.f, 0.f, 0.f, 0.f};
    float wsum = 0.f;

    int base = lo;
    for (; base + 3 < hi; base += 4) {
        int idx0 = base + ep;
        int idx1 = base + 2 + ep;
        int4 e0 = csr[idx0];
        int4 e1 = csr[idx1];
        float w0 = ewgt(e0, head);
        float w1 = ewgt(e1, head);
        uint4 r0 = *(const uint4*)(h1 + (size_t)e0.x * 256 + fl * 8);
        uint4 r1 = *(const uint4*)(h1 + (size_t)e1.x * 256 + fl * 8);
        fma8(r0, w0, acc);
        fma8(r1, w1, acc);
        wsum += w0 + w1;
    }
    for (; base < hi; base += 2) {
        int idx = base + ep;
        float w = 0.f;
        uint4 r = make_uint4(0, 0, 0, 0);
        if (idx < hi) {
            int4 e = csr[idx];
            w = ewgt(e, head);
            r = *(const uint4*)(h1 + (size_t)e.x * 256 + fl * 8);
        }
        fma8(r, w, acc);
        wsum += w;
    }

    // merge edge-parity halves: after this, BOTH halves hold the full sums
#pragma unroll
    for (int j = 0; j < 8; j++) acc[j] += __shfl_xor(acc[j], 32);
    wsum += __shfl_xor(wsum, 32);

    float inv = 1.f / (wsum + 1e-16f);

    // fused node2 epilogue: lane fl holds feats fl*8..fl*8+7 (all 64 lanes duplicate)
    float c0 = 0.f, c1 = 0.f;
#pragma unroll
    for (int half8 = 0; half8 < 2; ++half8) {
        float4 na = *(const float4*)&nA[fl * 8 + half8 * 4];
        float4 nb = *(const float4*)&nB[fl * 8 + half8 * 4];
        float naa[4] = {na.x, na.y, na.z, na.w};
        float nba[4] = {nb.x, nb.y, nb.z, nb.w};
#pragma unroll
        for (int j = 0; j < 4; j++) {
            int f = fl * 8 + half8 * 4 + j;
            float g = acc[half8 * 4 + j] * inv;
            float u = fmaf(g, naa[j], nba[j]);
            float t = u > 0.f ? u : expm1f(u);
            c0 = fmaf(t, W2[f * 2],     c0);
            c1 = fmaf(t, W2[f * 2 + 1], c1);
        }
    }
    c0 += __shfl_xor(c0, 1); c0 += __shfl_xor(c0, 2); c0 += __shfl_xor(c0, 4);
    c0 += __shfl_xor(c0, 8); c0 += __shfl_xor(c0, 16);
    c1 += __shfl_xor(c1, 1); c1 += __shfl_xor(c1, 2); c1 += __shfl_xor(c1, 4);
    c1 += __shfl_xor(c1, 8); c1 += __shfl_xor(c1, 16);

    if (lane == 0) {
        float as2 = c0 * attS2[0] + c1 * attS2[1];
        float ad2 = c0 * attD2[0] + c1 * attD2[1];
        pk2[wid] = make_float4(as2, ad2, c0, c1);
    }
}

// ---------------- agg2: 8 lanes per node, 16B pk2 gather + fused log_softmax ----------------
__global__ __launch_bounds__(256) void agg2_kernel(
    const int* __restrict__ offs, const int4* __restrict__ csr,
    const float4* __restrict__ pk2, const float* __restrict__ b2,
    float* __restrict__ out)
{
    int wid  = (blockIdx.x * 256 + threadIdx.x) >> 6;
    int lane = threadIdx.x & 63;
    int grp  = lane >> 3;
    int sub  = lane & 7;
    int n = wid * 8 + grp;
    if (n >= NN) return;
    int lo = offs[n], hi = offs[n + 1];
    float ad = pk2[n].y;

    float n0 = 0.f, n1 = 0.f, ws = 0.f;
    for (int i = lo + sub; i < hi; i += 8) {
        int s = csr[i].x;
        float4 p = pk2[s];
        float w = expf(lrelu(p.x + ad));
        n0 = fmaf(w, p.z, n0);
        n1 = fmaf(w, p.w, n1);
        ws += w;
    }
    n0 += __shfl_xor(n0, 1); n0 += __shfl_xor(n0, 2); n0 += __shfl_xor(n0, 4);
    n1 += __shfl_xor(n1, 1); n1 += __shfl_xor(n1, 2); n1 += __shfl_xor(n1, 4);
    ws += __shfl_xor(ws, 1); ws += __shfl_xor(ws, 2); ws += __shfl_xor(ws, 4);

    if (sub == 0) {
        float inv = 1.f / (ws + 1e-16f);
        float v0 = n0 * inv + b2[0];
        float v1 = n1 * inv + b2[1];
        float m = fmaxf(v0, v1);
        float lse = m + log1pf(expf(fminf(v0, v1) - m));
        *(float2*)&out[(size_t)n * 2] = make_float2(v0 - lse, v1 - lse);
    }
}

extern "C" void kernel_launch(void* const* d_in, const int* in_sizes, int n_in,
                              void* d_out, int out_size, void* d_ws, size_t ws_size,
                              hipStream_t stream)
{
    const float* x     = (const float*)d_in[0];
    const int*   ei    = (const int*)d_in[1];
    const float* W1    = (const float*)d_in[2];
    const float* attS1 = (const float*)d_in[3];
    const float* attD1 = (const float*)d_in[4];
    const float* b1    = (const float*)d_in[5];
    const float* gamma = (const float*)d_in[6];
    const float* beta  = (const float*)d_in[7];
    const float* rmean = (const float*)d_in[8];
    const float* rvar  = (const float*)d_in[9];
    const float* W2    = (const float*)d_in[10];
    const float* attS2 = (const float*)d_in[11];
    const float* attD2 = (const float*)d_in[12];
    const float* b2    = (const float*)d_in[13];
    float* out = (float*)d_out;

    float* f = (float*)d_ws;
    __half* h1    = (__half*)f;                  // N*256 halfs = N*128 floats
    float* asrc1  = f + (size_t)NN * 128;        // N*4
    float* adst1  = asrc1 + (size_t)NN * 4;      // N*4
    _Float16* W1f = (_Float16*)(adst1 + (size_t)NN * 4);  // 32768 halfs = 16384 floats
    float* nA     = adst1 + (size_t)NN * 4 + 16384;       // 256
    float* nB     = nA + 256;                    // 256
    float4* pk2   = (float4*)(nB + 256);         // N float4 (16B aligned)
    int4* csr     = (int4*)(pk2 + NN);           // E int4  (16B aligned)
    int* counts   = (int*)(csr + EE);            // N [zeroed in prep]
    int* offs     = counts + NN;                 // N+1
    int* cursor   = offs + (NN + 1);             // N
    int* bsum     = cursor + NN;                 // NB
    int* bbase    = bsum + NB;                   // NB

    prep_kernel<<<128, 256, 0, stream>>>(W1, b1, gamma, beta, rmean, rvar, W1f, nA, nB, counts);

    gemm1_hist<<<GB + HB, 256, 0, stream>>>(x, W1f, attS1, attD1, h1, asrc1, adst1, ei, counts);

    scan1_kernel<<<NB, 256, 0, stream>>>(counts, bsum);
    scan2_kernel<<<1, 128, 0, stream>>>(bsum, bbase, offs);
    scan3_kernel<<<NB, 256, 0, stream>>>(counts, bbase, offs, cursor);

    scatter_kernel<<<HB, 256, 0, stream>>>(ei, asrc1, adst1, cursor, csr);

    agg1_node2<<<(NN + 3) / 4, 256, 0, stream>>>(offs, csr, h1, nA, nB, W2, attS2, attD2, pk2);

    agg2_kernel<<<(NN + 31) / 32, 256, 0, stream>>>(offs, csr, pk2, b2, out);
}